// Round 1
// 311.077 us; speedup vs baseline: 1.0135x; 1.0135x over previous
//
#include <hip/hip_runtime.h>
#include <hip/hip_bf16.h>

typedef unsigned short u16;
typedef __attribute__((ext_vector_type(8))) short s16x8;
typedef __attribute__((ext_vector_type(4))) float f32x4;
typedef __attribute__((address_space(3))) u16 lds_u16;
typedef __attribute__((address_space(1))) const u16 g_u16;

#define CIN 256
#define COUT 256
#define NPIX 3136      // 56*56
#define CWROW 168      // was 160: +8 u16 pad per (ck,o) row -> 336B stride, gcd(336,128)=16
                       // kills the 8-way LDS bank conflict on the A-fragment ds_read_b128
#define CWPB (16 * COUT * CWROW)   // 688128 elems per batch
// xq layout: [b][ck(16)][h'(58)][w'(58)][ci(16)] bf16, halo rows/cols zero. row = 928 elems.
// cw layout: [b][ck(16)][o(256)][t(10)+pad][ci(16)] bf16, t=9 zero pad, elems 160..167 dead pad.

__device__ __forceinline__ u16 f2b(float f) {   // f32 -> bf16 bits, RNE
  union { float f; unsigned u; } c; c.f = f;
  unsigned r = (c.u + 0x7FFFu + ((c.u >> 16) & 1u)) >> 16;
  return (u16)r;
}

// ---------------- K0: transpose x -> xq + fused GAP — VERBATIM (proven) ----------------
// grid (58, 16, 16) = (h', ck, b), block 256. pooled must be zeroed before launch (holds raw sums).
__global__ __launch_bounds__(256)
void transpose_gap_kernel(const float* __restrict__ x, u16* __restrict__ xq,
                          float* __restrict__ pooled) {
  const int hp = blockIdx.x, ck = blockIdx.y, b = blockIdx.z;
  const int tid = threadIdx.x;
  const int wl = tid & 63, cg = tid >> 6;          // wave cg covers ci = cg*4 .. cg*4+3
  __shared__ __align__(16) u16 row[58 * 16];
  const int gr = hp - 1;
  const bool rowOK = ((unsigned)gr < 56u);
  float v[4];
  const size_t base = ((size_t)b * CIN + ck * 16 + cg * 4) * NPIX + (size_t)(rowOK ? gr : 0) * 56;
#pragma unroll
  for (int i = 0; i < 4; ++i) {
    float f = 0.f;
    if (rowOK && wl < 56) f = x[base + (size_t)i * NPIX + wl];
    v[i] = f;
    if (wl < 56)       row[(wl + 1) * 16 + cg * 4 + i] = f2b(f);
    else if (wl == 56) row[0 * 16 + cg * 4 + i] = 0;
    else if (wl == 57) row[57 * 16 + cg * 4 + i] = 0;
  }
  if (rowOK) {       // GAP partials: all 64 lanes of this wave share the same 4 ci's
#pragma unroll
    for (int i = 0; i < 4; ++i) {
      float s = v[i];
      for (int off = 32; off > 0; off >>= 1) s += __shfl_down(s, off, 64);
      if (wl == 0) atomicAdd(&pooled[b * CIN + ck * 16 + cg * 4 + i], s);
    }
  }
  __syncthreads();
  uint4* dst = (uint4*)(xq + ((size_t)(b * 16 + ck) * 58 + hp) * 928);
  if (tid < 116) dst[tid] = ((const uint4*)row)[tid];
}

// ---------------- K3: combine (routing fused) — stride-168 update only ----------------
// grid 256 (one per o), block 256. W held in 72 regs; r computed in-block from pooled SUMS.
__global__ __launch_bounds__(256)
void combine_kernel(const float* __restrict__ W, const float* __restrict__ pooled,
                    const float* __restrict__ rw, const float* __restrict__ rb,
                    u16* __restrict__ cw) {
  const int o = blockIdx.x, tid = threadIdx.x;
  __shared__ float rs[128];
  if (tid < 128) {                       // routing: r[b][e]
    int b = tid >> 3, e = tid & 7;
    float s = rb[e];
    const float* pb = pooled + b * CIN;
    const float* we = rw + e * CIN;
    for (int c = 0; c < CIN; ++c) s += (pb[c] * (1.f / 3136.f)) * we[c];
    rs[tid] = 1.f / (1.f + __expf(-s));
  }
  float wreg[8][9];
#pragma unroll
  for (int e = 0; e < 8; ++e) {
    const float* wp = W + ((size_t)(e * COUT + o)) * 2304 + tid;
#pragma unroll
    for (int k = 0; k < 9; ++k) wreg[e][k] = wp[k * 256];
  }
  int off2[9];                            // store offsets (loop-invariant over b)
#pragma unroll
  for (int k = 0; k < 9; ++k) {
    int j = tid + k * 256, ci = j / 9, t = j - ci * 9;
    off2[k] = ((ci >> 4) * 256 + o) * CWROW + t * 16 + (ci & 15);
  }
  const int offz = ((tid >> 4) * 256 + o) * CWROW + 144 + (tid & 15);
  __syncthreads();
  for (int b = 0; b < 16; ++b) {
    float rv[8];
#pragma unroll
    for (int e = 0; e < 8; ++e) rv[e] = rs[b * 8 + e];
    u16* dst = cw + (size_t)b * CWPB;
#pragma unroll
    for (int k = 0; k < 9; ++k) {
      float a = 0.f;
#pragma unroll
      for (int e = 0; e < 8; ++e) a += rv[e] * wreg[e][k];
      dst[off2[k]] = f2b(a);
    }
    dst[offz] = 0;                        // tap-9 zero pad
  }
}

// ---------------- K4: conv — double-buffered staging + XCD-local block mapping ----------------
// grid 448 linear. Decode: xcd = l&7 (dispatch round-robins XCDs), each XCD owns b = xcd then
// b = xcd+8 (3.1 MB working set per phase -> fits 4 MB XCD L2). Within a b: o-block major so the
// cw panel is reused by 7 consecutive h-blocks.
__global__ __launch_bounds__(256)
void conv_kernel(const u16* __restrict__ xq, const u16* __restrict__ cw,
                 const float* __restrict__ bng, const float* __restrict__ bnb,
                 const float* __restrict__ bnm, const float* __restrict__ bnv,
                 float* __restrict__ out) {
  const int l = blockIdx.x;
  const int xcd = l & 7, s = l >> 3;          // s in 0..55
  const int bb = (s >= 28) ? 1 : 0;
  const int b = xcd + 8 * bb;
  const int r = s - 28 * bb;                  // 0..27 = 4 o-blocks x 7 h-blocks
  const int ob = r / 7;
  const int o0 = ob * 64, h0 = (r - ob * 7) * 8;
  const int tid = threadIdx.x;
  const int wv = tid >> 6, lane = tid & 63, quad = lane >> 4, ln = lane & 15;

  __shared__ __align__(16) u16 xs[2][19 * 512];     // 2 x 19,456 B
  __shared__ __align__(16) u16 as_[2][64 * CWROW];  // 2 x 21,504 B  -> total 81,920 B (2 blk/CU)

  f32x4 acc[4][7];
#pragma unroll
  for (int ms = 0; ms < 4; ++ms)
#pragma unroll
    for (int ns = 0; ns < 7; ++ns) acc[ms][ns] = (f32x4){0.f, 0.f, 0.f, 0.f};

  int bsite[7];
#pragma unroll
  for (int ns = 0; ns < 7; ++ns) {
    int pi = ns * 16 + ln;
    int hr = (pi >= 56) ? 1 : 0;
    int wc = pi - hr * 56;
    bsite[ns] = ((2 * wv + hr) * 58 + wc) * 16;
  }

  // issue one ck-tile's staging loads into LDS buffer `buf` (no wait here)
  auto STAGE = [&](int ck, int buf) {
    const u16* xsrc = xq + ((size_t)(b * 16 + ck) * 58 + h0) * 928;      // 10 rows contiguous
    const u16* asrc = cw + (size_t)b * CWPB + ((size_t)ck * COUT + o0) * CWROW; // 64 o's contig
    for (int g = wv; g < 40; g += 4) {
      if (g < 19)
        __builtin_amdgcn_global_load_lds((g_u16*)(xsrc + g * 512 + lane * 8),
                                         (lds_u16*)(&xs[buf][g * 512]), 16, 0, 0);
      else
        __builtin_amdgcn_global_load_lds((g_u16*)(asrc + (g - 19) * 512 + lane * 8),
                                         (lds_u16*)(&as_[buf][(g - 19) * 512]), 16, 0, 0);
    }
  };

  auto COMPUTE = [&](int buf) {
#pragma unroll
    for (int tp = 0; tp < 5; ++tp) {
      int t = tp * 2 + (quad >> 1);
      int dy, dx;
      if (t < 9) { dy = t / 3; dx = t - dy * 3; } else { dy = 1; dx = 1; }  // t=9: zero weights
      const int boff = (dy * 58 + dx) * 16 + (quad & 1) * 8;
      s16x8 af[4];
#pragma unroll
      for (int ms = 0; ms < 4; ++ms)
        af[ms] = *(const s16x8*)&as_[buf][(ms * 16 + ln) * CWROW + tp * 32 + quad * 8];
#pragma unroll
      for (int ns = 0; ns < 7; ++ns) {
        s16x8 bfr = *(const s16x8*)&xs[buf][bsite[ns] + boff];
#pragma unroll
        for (int ms = 0; ms < 4; ++ms)
          acc[ms][ns] = __builtin_amdgcn_mfma_f32_16x16x32_bf16(af[ms], bfr, acc[ms][ns], 0, 0, 0);
      }
    }
  };

  // T3-minimum double-buffer: prefetch ck+1 while computing ck; the single __syncthreads per
  // ck supplies both the vmcnt(0) drain (next tile ready) and the buffer-reuse barrier.
  STAGE(0, 0);
  __syncthreads();
  for (int ck = 0; ck < 16; ck += 2) {
    STAGE(ck + 1, 1);
    COMPUTE(0);
    __syncthreads();
    if (ck < 14) STAGE(ck + 2, 0);
    COMPUTE(1);
    __syncthreads();
  }

  // ---- epilogue: BN + SiLU, f32 store ----
#pragma unroll
  for (int ms = 0; ms < 4; ++ms) {
#pragma unroll
    for (int rr = 0; rr < 4; ++rr) {
      int o = o0 + ms * 16 + quad * 4 + rr;     // C/D: row = quad*4 + reg
      float inv = bng[o] * rsqrtf(bnv[o] + 1e-5f);
      float bias = bnb[o] - bnm[o] * inv;
      float* obp = out + ((size_t)(b * COUT + o)) * NPIX;
#pragma unroll
      for (int ns = 0; ns < 7; ++ns) {
        int pi = ns * 16 + ln;                  // C/D: col = lane&15
        int hr = (pi >= 56) ? 1 : 0;
        int wc = pi - hr * 56;
        int hg = h0 + 2 * wv + hr;
        float v = acc[ms][ns][rr] * inv + bias;
        v = v / (1.f + __expf(-v));             // SiLU
        obp[hg * 56 + wc] = v;
      }
    }
  }
}

extern "C" void kernel_launch(void* const* d_in, const int* in_sizes, int n_in,
                              void* d_out, int out_size, void* d_ws, size_t ws_size,
                              hipStream_t stream) {
  const float* x   = (const float*)d_in[0];
  const float* rw  = (const float*)d_in[1];
  const float* rb  = (const float*)d_in[2];
  const float* W   = (const float*)d_in[3];
  const float* bng = (const float*)d_in[4];
  const float* bnb = (const float*)d_in[5];
  const float* bnm = (const float*)d_in[6];
  const float* bnv = (const float*)d_in[7];
  float* out = (float*)d_out;

  char* wsb = (char*)d_ws;
  // cw: 16*16*256*168*2                      = 22,020,096 B
  // xq: 16*16*58*58*16*2 = 27,557,888 (+1 KiB staging over-read pad) = 27,558,912 B
  //     (old layout sized xq 3,072 B short -> its tail clobbered pooled[0..767]; fixed)
  // pooled: 16*256*4                         =     16,384 B   (total 49,595,392 B)
  u16*  cw     = (u16*)wsb;
  u16*  xq     = (u16*)(wsb + 22020096);
  float* pooled = (float*)(wsb + 22020096 + 27558912);

  hipMemsetAsync(pooled, 0, 16 * CIN * sizeof(float), stream);
  transpose_gap_kernel<<<dim3(58, 16, 16), 256, 0, stream>>>(x, xq, pooled);
  combine_kernel<<<256, 256, 0, stream>>>(W, pooled, rw, rb, cw);
  conv_kernel<<<dim3(448), 256, 0, stream>>>(xq, cw, bng, bnb, bnm, bnv, out);
}

// Round 2
// 230.668 us; speedup vs baseline: 1.3667x; 1.3486x over previous
//
#include <hip/hip_runtime.h>
#include <hip/hip_bf16.h>

typedef unsigned short u16;
typedef __attribute__((ext_vector_type(8))) short s16x8;
typedef __attribute__((ext_vector_type(4))) float f32x4;
typedef __attribute__((address_space(3))) u16 lds_u16;
typedef __attribute__((address_space(1))) const u16 g_u16;

#define CIN 256
#define COUT 256
#define NPIX 3136      // 56*56
#define CWROW 168      // 336B stride, gcd(336,128)=16: kills 8-way LDS conflict on A-frag reads
#define CWPB (16 * COUT * CWROW)   // 688128 elems per batch
// xq layout: [b][ck(16)][h'(58)][w'(58)][ci(16)] bf16, halo rows/cols zero. row = 928 elems.
// cw layout: [b][ck(16)][o(256)][t(10)+pad][ci(16)] bf16, t=9 zero pad, elems 160..167 dead pad.

__device__ __forceinline__ u16 f2b(float f) {   // f32 -> bf16 bits, RNE
  union { float f; unsigned u; } c; c.f = f;
  unsigned r = (c.u + 0x7FFFu + ((c.u >> 16) & 1u)) >> 16;
  return (u16)r;
}

// ---------------- K0: transpose x -> xq + fused GAP — REWRITTEN (vectorized, 8 rows/block) -----
// grid (7, 16, 16) = (hg, ck, b), block 256. Each lane owns fixed ci = tid>>4, loads 7x float4
// (coalesced 256B per 16-lane group). GAP: per-lane reg accumulator + width-16 shuffle reduce.
// LDS transpose tile is 928 16B-units, XOR-swizzled u^=((u>>3)&7) (bijective, same map on write
// and read) so the u16 scatter (w'-step-4 would alias one bank) spreads over 8 bank groups while
// read-out stays contiguous ds_read_b128 -> coalesced uint4 global stores (14.8KB contiguous).
__global__ __launch_bounds__(256)
void transpose_gap_kernel(const float* __restrict__ x, u16* __restrict__ xq,
                          float* __restrict__ pooled) {
  const int hg = blockIdx.x, ck = blockIdx.y, b = blockIdx.z;
  const int tid = threadIdx.x;
  const int ci = tid >> 4, sub = tid & 15;
  __shared__ __align__(16) u16 tile[928 * 8];   // 14,848 B

  if (tid < 32) {                 // zero w'-halo units (w' = 0, 57 -> c in {0,1,114,115})
    int r = tid >> 2, c4 = tid & 3;
    int u = r * 116 + (c4 < 2 ? c4 : 112 + c4);
    int us = u ^ ((u >> 3) & 7);
    *(uint4*)&tile[us * 8] = (uint4){0, 0, 0, 0};
  }

  const float* src = x + ((size_t)(b * CIN + ck * 16 + ci) * NPIX + (size_t)hg * 448);
  float s = 0.f;
#pragma unroll
  for (int it = 0; it < 7; ++it) {
    int p = it * 16 + sub;                      // [0,112): 8 rows x 14 float4
    int row = p / 14, wq = p - row * 14;
    float4 v = *(const float4*)(src + p * 4);
    s += v.x + v.y + v.z + v.w;
    u16 q[4] = { f2b(v.x), f2b(v.y), f2b(v.z), f2b(v.w) };
#pragma unroll
    for (int k = 0; k < 4; ++k) {
      int wp = wq * 4 + 1 + k;                  // w' in [1,56]
      int u = (row * 58 + wp) * 2 + (ci >> 3);
      int us = u ^ ((u >> 3) & 7);
      tile[us * 8 + (ci & 7)] = q[k];
    }
  }
  for (int off = 8; off; off >>= 1) s += __shfl_down(s, off, 16);  // reduce 16 lanes sharing ci
  if (sub == 0) atomicAdd(&pooled[b * CIN + ck * 16 + ci], s);

  __syncthreads();
  uint4* dst = (uint4*)(xq + ((size_t)(b * 16 + ck) * 58 + hg * 8 + 1) * 928);
  for (int idx = tid; idx < 928; idx += 256) {  // 8 rows x 116 uint4, contiguous
    int us = idx ^ ((idx >> 3) & 7);
    dst[idx] = *(const uint4*)&tile[us * 8];
  }
  if (hg == 0 && tid < 116)                     // halo row h'=0
    ((uint4*)(xq + ((size_t)(b * 16 + ck) * 58) * 928))[tid] = (uint4){0, 0, 0, 0};
  if (hg == 6 && tid < 116)                     // halo row h'=57
    ((uint4*)(xq + ((size_t)(b * 16 + ck) * 58 + 57) * 928))[tid] = (uint4){0, 0, 0, 0};
}

// ---------------- K3: combine (routing fused) — VERBATIM (proven) ----------------
__global__ __launch_bounds__(256)
void combine_kernel(const float* __restrict__ W, const float* __restrict__ pooled,
                    const float* __restrict__ rw, const float* __restrict__ rb,
                    u16* __restrict__ cw) {
  const int o = blockIdx.x, tid = threadIdx.x;
  __shared__ float rs[128];
  if (tid < 128) {                       // routing: r[b][e]
    int b = tid >> 3, e = tid & 7;
    float s = rb[e];
    const float* pb = pooled + b * CIN;
    const float* we = rw + e * CIN;
    for (int c = 0; c < CIN; ++c) s += (pb[c] * (1.f / 3136.f)) * we[c];
    rs[tid] = 1.f / (1.f + __expf(-s));
  }
  float wreg[8][9];
#pragma unroll
  for (int e = 0; e < 8; ++e) {
    const float* wp = W + ((size_t)(e * COUT + o)) * 2304 + tid;
#pragma unroll
    for (int k = 0; k < 9; ++k) wreg[e][k] = wp[k * 256];
  }
  int off2[9];                            // store offsets (loop-invariant over b)
#pragma unroll
  for (int k = 0; k < 9; ++k) {
    int j = tid + k * 256, ci = j / 9, t = j - ci * 9;
    off2[k] = ((ci >> 4) * 256 + o) * CWROW + t * 16 + (ci & 15);
  }
  const int offz = ((tid >> 4) * 256 + o) * CWROW + 144 + (tid & 15);
  __syncthreads();
  for (int b = 0; b < 16; ++b) {
    float rv[8];
#pragma unroll
    for (int e = 0; e < 8; ++e) rv[e] = rs[b * 8 + e];
    u16* dst = cw + (size_t)b * CWPB;
#pragma unroll
    for (int k = 0; k < 9; ++k) {
      float a = 0.f;
#pragma unroll
      for (int e = 0; e < 8; ++e) a += rv[e] * wreg[e][k];
      dst[off2[k]] = f2b(a);
    }
    dst[offz] = 0;                        // tap-9 zero pad
  }
}

// ---------------- K4: conv — VERBATIM (double-buffered + XCD-local, proven this round) --------
__global__ __launch_bounds__(256)
void conv_kernel(const u16* __restrict__ xq, const u16* __restrict__ cw,
                 const float* __restrict__ bng, const float* __restrict__ bnb,
                 const float* __restrict__ bnm, const float* __restrict__ bnv,
                 float* __restrict__ out) {
  const int l = blockIdx.x;
  const int xcd = l & 7, s = l >> 3;          // s in 0..55
  const int bb = (s >= 28) ? 1 : 0;
  const int b = xcd + 8 * bb;
  const int r = s - 28 * bb;                  // 0..27 = 4 o-blocks x 7 h-blocks
  const int ob = r / 7;
  const int o0 = ob * 64, h0 = (r - ob * 7) * 8;
  const int tid = threadIdx.x;
  const int wv = tid >> 6, lane = tid & 63, quad = lane >> 4, ln = lane & 15;

  __shared__ __align__(16) u16 xs[2][19 * 512];     // 2 x 19,456 B
  __shared__ __align__(16) u16 as_[2][64 * CWROW];  // 2 x 21,504 B  -> total 81,920 B (2 blk/CU)

  f32x4 acc[4][7];
#pragma unroll
  for (int ms = 0; ms < 4; ++ms)
#pragma unroll
    for (int ns = 0; ns < 7; ++ns) acc[ms][ns] = (f32x4){0.f, 0.f, 0.f, 0.f};

  int bsite[7];
#pragma unroll
  for (int ns = 0; ns < 7; ++ns) {
    int pi = ns * 16 + ln;
    int hr = (pi >= 56) ? 1 : 0;
    int wc = pi - hr * 56;
    bsite[ns] = ((2 * wv + hr) * 58 + wc) * 16;
  }

  auto STAGE = [&](int ck, int buf) {
    const u16* xsrc = xq + ((size_t)(b * 16 + ck) * 58 + h0) * 928;      // 10 rows contiguous
    const u16* asrc = cw + (size_t)b * CWPB + ((size_t)ck * COUT + o0) * CWROW; // 64 o's contig
    for (int g = wv; g < 40; g += 4) {
      if (g < 19)
        __builtin_amdgcn_global_load_lds((g_u16*)(xsrc + g * 512 + lane * 8),
                                         (lds_u16*)(&xs[buf][g * 512]), 16, 0, 0);
      else
        __builtin_amdgcn_global_load_lds((g_u16*)(asrc + (g - 19) * 512 + lane * 8),
                                         (lds_u16*)(&as_[buf][(g - 19) * 512]), 16, 0, 0);
    }
  };

  auto COMPUTE = [&](int buf) {
#pragma unroll
    for (int tp = 0; tp < 5; ++tp) {
      int t = tp * 2 + (quad >> 1);
      int dy, dx;
      if (t < 9) { dy = t / 3; dx = t - dy * 3; } else { dy = 1; dx = 1; }  // t=9: zero weights
      const int boff = (dy * 58 + dx) * 16 + (quad & 1) * 8;
      s16x8 af[4];
#pragma unroll
      for (int ms = 0; ms < 4; ++ms)
        af[ms] = *(const s16x8*)&as_[buf][(ms * 16 + ln) * CWROW + tp * 32 + quad * 8];
#pragma unroll
      for (int ns = 0; ns < 7; ++ns) {
        s16x8 bfr = *(const s16x8*)&xs[buf][bsite[ns] + boff];
#pragma unroll
        for (int ms = 0; ms < 4; ++ms)
          acc[ms][ns] = __builtin_amdgcn_mfma_f32_16x16x32_bf16(af[ms], bfr, acc[ms][ns], 0, 0, 0);
      }
    }
  };

  STAGE(0, 0);
  __syncthreads();
  for (int ck = 0; ck < 16; ck += 2) {
    STAGE(ck + 1, 1);
    COMPUTE(0);
    __syncthreads();
    if (ck < 14) STAGE(ck + 2, 0);
    COMPUTE(1);
    __syncthreads();
  }

  // ---- epilogue: BN + SiLU, f32 store ----
#pragma unroll
  for (int ms = 0; ms < 4; ++ms) {
#pragma unroll
    for (int rr = 0; rr < 4; ++rr) {
      int o = o0 + ms * 16 + quad * 4 + rr;     // C/D: row = quad*4 + reg
      float inv = bng[o] * rsqrtf(bnv[o] + 1e-5f);
      float bias = bnb[o] - bnm[o] * inv;
      float* obp = out + ((size_t)(b * COUT + o)) * NPIX;
#pragma unroll
      for (int ns = 0; ns < 7; ++ns) {
        int pi = ns * 16 + ln;                  // C/D: col = lane&15
        int hr = (pi >= 56) ? 1 : 0;
        int wc = pi - hr * 56;
        int hg = h0 + 2 * wv + hr;
        float v = acc[ms][ns][rr] * inv + bias;
        v = v / (1.f + __expf(-v));             // SiLU
        obp[hg * 56 + wc] = v;
      }
    }
  }
}

extern "C" void kernel_launch(void* const* d_in, const int* in_sizes, int n_in,
                              void* d_out, int out_size, void* d_ws, size_t ws_size,
                              hipStream_t stream) {
  const float* x   = (const float*)d_in[0];
  const float* rw  = (const float*)d_in[1];
  const float* rb  = (const float*)d_in[2];
  const float* W   = (const float*)d_in[3];
  const float* bng = (const float*)d_in[4];
  const float* bnb = (const float*)d_in[5];
  const float* bnm = (const float*)d_in[6];
  const float* bnv = (const float*)d_in[7];
  float* out = (float*)d_out;

  char* wsb = (char*)d_ws;
  // cw: 16*16*256*168*2 = 22,020,096 B ; xq: 16*16*58*58*16*2 (+1 KiB pad) = 27,558,912 B
  // pooled: 16*256*4 = 16,384 B   (total 49,595,392 B)
  u16*  cw     = (u16*)wsb;
  u16*  xq     = (u16*)(wsb + 22020096);
  float* pooled = (float*)(wsb + 22020096 + 27558912);

  hipMemsetAsync(pooled, 0, 16 * CIN * sizeof(float), stream);
  transpose_gap_kernel<<<dim3(7, 16, 16), 256, 0, stream>>>(x, xq, pooled);
  combine_kernel<<<256, 256, 0, stream>>>(W, pooled, rw, rb, cw);
  conv_kernel<<<dim3(448), 256, 0, stream>>>(xq, cw, bng, bnb, bnm, bnv, out);
}